// Round 1
// baseline (235.948 us; speedup 1.0000x reference)
//
#include <hip/hip_runtime.h>

#define B_TOTAL 32768
#define NF 200
#define D_IN 5
#define NH 15
#define NOUT 30

// ---------------- Precompute: fold W1*W2 and b1*W2+b2 into d_ws ----------------
__global__ __launch_bounds__(256) void precompute_kernel(
    const float* __restrict__ W1, const float* __restrict__ b1,
    const float* __restrict__ W2, const float* __restrict__ b2,
    float* __restrict__ Wc, float* __restrict__ bc)
{
    int idx = blockIdx.x * 256 + threadIdx.x;
    if (idx < NF * D_IN * NOUT) {
        int o  = idx % NOUT;
        int fi = idx / NOUT;
        int i  = fi % D_IN;
        int f  = fi / D_IN;
        float s = 0.f;
        #pragma unroll
        for (int h = 0; h < NH; ++h)
            s = fmaf(W1[(f * D_IN + i) * NH + h], W2[(f * NH + h) * NOUT + o], s);
        Wc[idx] = s;   // layout [f][i][o], idx == (f*D_IN+i)*NOUT + o
    } else if (idx < NF * D_IN * NOUT + NF * NOUT) {
        int k = idx - NF * D_IN * NOUT;
        int o = k % NOUT;
        int f = k / NOUT;
        float s = b2[f * NOUT + o];
        #pragma unroll
        for (int h = 0; h < NH; ++h)
            s = fmaf(b1[f * NH + h], W2[(f * NH + h) * NOUT + o], s);
        bc[k] = s;     // layout [f][o]
    }
}

// ---------------- Main fused kernel ----------------
#define BTILE 64          // batch rows per block
#define NSUB 8            // waves per block; each wave owns 25 f's
#define FC 40             // f's per LDS chunk
#define NCHUNK 5          // 200 / 40
#define FSUB 5            // f's per sub per chunk
#define ROWSTRIDE 201     // FC*D_IN + 1 pad -> bank stride 9 (coprime 32)

__global__ __launch_bounds__(512, 4) void mlp_kernel(
    const float* __restrict__ y, const float* __restrict__ Wc,
    const float* __restrict__ bc, const float* __restrict__ w3,
    const float* __restrict__ b3, float* __restrict__ out)
{
    __shared__ float ytile[BTILE * ROWSTRIDE];
    __shared__ float red[BTILE * NSUB];

    const int tid     = threadIdx.x;
    const int b_local = tid & 63;
    const int sub     = tid >> 6;                          // 0..7, wave-uniform
    const int sub_u   = __builtin_amdgcn_readfirstlane(sub); // provably uniform
    const int b0      = blockIdx.x * BTILE;

    float acc = 0.f;

    for (int c = 0; c < NCHUNK; ++c) {
        // ---- stage y[b0..b0+63][c*FC .. c*FC+FC)[.] into LDS, float4 coalesced
        for (int j = tid; j < BTILE * (FC * D_IN / 4); j += 512) {   // 3200 float4s
            int row  = j / (FC * D_IN / 4);       // /50
            int col4 = j - row * (FC * D_IN / 4);
            const float4 v = *(const float4*)&y[(size_t)(b0 + row) * (NF * D_IN)
                                                + c * (FC * D_IN) + col4 * 4];
            float* dst = &ytile[row * ROWSTRIDE + col4 * 4];
            dst[0] = v.x; dst[1] = v.y; dst[2] = v.z; dst[3] = v.w;
        }
        __syncthreads();

        const float* yrow = &ytile[b_local * ROWSTRIDE + sub * (FSUB * D_IN)];
        const int fbase = c * FC + sub_u * FSUB;

        #pragma unroll 1
        for (int ff = 0; ff < FSUB; ++ff) {
            const int f = fbase + ff;
            const float y0 = yrow[ff * 5 + 0];
            const float y1 = yrow[ff * 5 + 1];
            const float y2 = yrow[ff * 5 + 2];
            const float y3 = yrow[ff * 5 + 3];
            const float y4 = yrow[ff * 5 + 4];
            const float* __restrict__ wf  = Wc + f * (D_IN * NOUT);  // uniform addr
            const float* __restrict__ bcf = bc + f * NOUT;
            const float* __restrict__ w3f = w3 + f * NOUT;
            #pragma unroll
            for (int o = 0; o < NOUT; ++o) {
                float z = bcf[o];
                z = fmaf(y0, wf[o          ], z);
                z = fmaf(y1, wf[NOUT   + o ], z);
                z = fmaf(y2, wf[2*NOUT + o ], z);
                z = fmaf(y3, wf[3*NOUT + o ], z);
                z = fmaf(y4, wf[4*NOUT + o ], z);
                acc = fmaf(fmaxf(z, 0.f), w3f[o], acc);
            }
        }
        __syncthreads();
    }

    // ---- reduce the 8 sub-partials per batch row
    red[b_local * NSUB + sub] = acc;
    __syncthreads();
    if (tid < BTILE) {
        float s = b3[0];
        #pragma unroll
        for (int k = 0; k < NSUB; ++k) s += red[tid * NSUB + k];
        out[b0 + tid] = s;
    }
}

extern "C" void kernel_launch(void* const* d_in, const int* in_sizes, int n_in,
                              void* d_out, int out_size, void* d_ws, size_t ws_size,
                              hipStream_t stream) {
    const float* y  = (const float*)d_in[0];
    const float* W1 = (const float*)d_in[1];
    const float* b1 = (const float*)d_in[2];
    const float* W2 = (const float*)d_in[3];
    const float* b2 = (const float*)d_in[4];
    const float* W3 = (const float*)d_in[5];
    const float* b3 = (const float*)d_in[6];
    float* out = (float*)d_out;

    float* Wc = (float*)d_ws;                    // 30000 floats
    float* bc = Wc + NF * D_IN * NOUT;           // 6000 floats (total 144 KB of ws)

    const int total_pre = NF * D_IN * NOUT + NF * NOUT;  // 36000
    precompute_kernel<<<(total_pre + 255) / 256, 256, 0, stream>>>(W1, b1, W2, b2, Wc, bc);
    mlp_kernel<<<B_TOTAL / BTILE, 512, 0, stream>>>(y, Wc, bc, W3, b3, out);
}